// Round 3
// baseline (809.400 us; speedup 1.0000x reference)
//
#include <hip/hip_runtime.h>
#include <cstdint>

// Problem constants
#define B_  4
#define H_  16
#define S_  2048
#define DH_ 64
#define E_  1024
#define M_  (B_ * S_)   // 8192 rows for all projection GEMMs

typedef __attribute__((ext_vector_type(8))) __bf16 bf16x8;
typedef __attribute__((ext_vector_type(4))) __bf16 bf16x4;
typedef __attribute__((ext_vector_type(4))) float  f32x4;

// fp32 -> bf16 (round-to-nearest-even), bit-level
__device__ __forceinline__ uint16_t f2bf(float f) {
    union { float f; uint32_t u; } v; v.f = f;
    uint32_t u = v.u;
    uint32_t r = (u + 0x7fffu + ((u >> 16) & 1u)) >> 16;
    return (uint16_t)r;
}
__device__ __forceinline__ uint32_t pack2(float a, float b) {
    return (uint32_t)f2bf(a) | ((uint32_t)f2bf(b) << 16);
}

// hardware packed fp32->bf16 (RNE), 2 values -> 1 dword.  lo in [15:0].
__device__ __forceinline__ uint32_t cvt_pk_bf16(float lo, float hi) {
    uint32_t r;
    asm("v_cvt_pk_bf16_f32 %0, %1, %2" : "=v"(r) : "v"(lo), "v"(hi));
    return r;
}

// 2^x directly on the trans pipe (v_exp_f32 computes 2^S0)
__device__ __forceinline__ float exp2_fast(float x) {
#if __has_builtin(__builtin_amdgcn_exp2f)
    return __builtin_amdgcn_exp2f(x);
#else
    float r; asm("v_exp_f32 %0, %1" : "=v"(r) : "v"(x)); return r;
#endif
}

// async global->LDS, 16B per lane. LDS dest is wave-uniform base; HW adds lane*16.
__device__ __forceinline__ void glds16(const void* g, void* lds_base) {
    __builtin_amdgcn_global_load_lds(
        (const __attribute__((address_space(1))) uint32_t*)g,
        (__attribute__((address_space(3))) uint32_t*)lds_base, 16, 0, 0);
}

// ---------------------------------------------------------------------------
// Kernel 1 (fused prep): cast Wq/Wk/Wv/Wo and query/key/value fp32 -> bf16.
// ---------------------------------------------------------------------------
__global__ void prep_kernel(const float* __restrict__ q, const float* __restrict__ k,
                            const float* __restrict__ v,
                            const float* __restrict__ w0, const float* __restrict__ w1,
                            const float* __restrict__ w2, const float* __restrict__ w3,
                            uint16_t* __restrict__ wbf,
                            uint16_t* __restrict__ qa, uint16_t* __restrict__ ka,
                            uint16_t* __restrict__ va) {
    int bid = blockIdx.x;
    const float* src; uint16_t* dst; int base;
    if (bid < 2048) {
        int i = bid * 256 + threadIdx.x;
        base = i * 8;                         // [0, 4*2^20)
        int wsel = base >> 20;
        src = (wsel == 0) ? w0 : (wsel == 1) ? w1 : (wsel == 2) ? w2 : w3;
        dst = wbf + base;
        base &= 1048575;
    } else {
        int r = bid - 2048;                   // [0, 12288)
        int sel = r >> 12;                    // 4096 blocks per activation
        int i = (r & 4095) * 256 + threadIdx.x;
        base = i * 8;                         // [0, 2^23)
        src = (sel == 0) ? q : (sel == 1) ? k : v;
        dst = ((sel == 0) ? qa : (sel == 1) ? ka : va) + base;
    }
    float4 a = *(const float4*)(src + base);
    float4 b = *(const float4*)(src + base + 4);
    uint4 o;
    o.x = pack2(a.x, a.y); o.y = pack2(a.z, a.w);
    o.z = pack2(b.x, b.y); o.w = pack2(b.z, b.w);
    *(uint4*)dst = o;
}

// ---------------------------------------------------------------------------
// Mask int32 -> bitmask, written in the TRANSPOSED layout the attention
// kernel consumes: u32 index = ((((b*32+qt)*4 + wv)*16 + it)*4 + quad)*4 + mt)*4 + r
// where word (it,wv) covers cols [it*128+wv*32, +32) and the q-row is
// qt*64 + mt*16 + quad*4 + r.  This lets each attn lane fetch its 16 mask
// words per iteration as 4 x dwordx4 (broadcast within a quad).
// bit=1 -> masked.
// ---------------------------------------------------------------------------
__global__ void mask_bits_kernel(const int* __restrict__ mask, uint32_t* __restrict__ bits) {
    int idx = blockIdx.x * 256 + threadIdx.x;      // element in [B*S*S)
    uint64_t bl = __ballot(mask[idx] != 0);        // 64 consecutive cols of one row
    if ((threadIdx.x & 63) == 0) {
        int col = idx & 2047;                      // base col of this wave-group
        int row = (idx >> 11) & 2047;
        int b   = idx >> 22;
        int qt = row >> 6, sl = row & 63;
        int mt = sl >> 4, quad = (sl >> 2) & 3, r = sl & 3;
        int c0 = col >> 5;                         // even word index
        int it0 = c0 >> 2, wv0 = c0 & 3;
        int it1 = (c0 + 1) >> 2, wv1 = (c0 + 1) & 3;
        size_t bq = (size_t)(b * 32 + qt);
        size_t i0 = ((((bq * 4 + wv0) * 16 + it0) * 4 + quad) * 4 + mt) * 4 + r;
        size_t i1 = ((((bq * 4 + wv1) * 16 + it1) * 4 + quad) * 4 + mt) * 4 + r;
        bits[i0] = (uint32_t)bl;
        bits[i1] = (uint32_t)(bl >> 32);
    }
}

// ---------------------------------------------------------------------------
// Kernel 2: C = A @ W^T + bias GEMM, bf16 in, global_load_lds staging with
// XOR-chunk swizzle (phys_chunk = chunk ^ (row&7)) so frag reads are <=2-way.
//   mode 0: fp32 out [8192,1024]
//   mode 1: bf16 out scattered to [B,H,S,Dh]
//   mode 2: bf16 out scattered to [B,H,Dh,S] (V transposed)
// q is scaled by 0.125*log2(e) so attention can use exp2 directly.
// ---------------------------------------------------------------------------
__global__ __launch_bounds__(256, 2)
void gemm_bt_kernel(const uint16_t* __restrict__ A0, const uint16_t* __restrict__ A1,
                    const uint16_t* __restrict__ A2,
                    const uint16_t* __restrict__ Bw0,
                    const float* __restrict__ bias0, const float* __restrict__ bias1,
                    const float* __restrict__ bias2,
                    void* __restrict__ out0, void* __restrict__ out1,
                    void* __restrict__ out2,
                    int multi) {
    const int z = blockIdx.z;
    const uint16_t* A  = (z == 0) ? A0 : (z == 1) ? A1 : A2;
    const uint16_t* Bw = Bw0 + (size_t)z * 1048576;
    const float* bias  = (z == 0) ? bias0 : (z == 1) ? bias1 : bias2;
    void* out          = (z == 0) ? out0 : (z == 1) ? out1 : out2;
    const float scale  = (multi && z == 0) ? 0.18033688f : 1.0f;  // 0.125*log2e
    const int mode     = multi ? ((z == 2) ? 2 : 1) : 0;

    const int m0 = blockIdx.y * 128;
    const int n0 = blockIdx.x * 128;

    __shared__ __align__(16) uint16_t As[128 * 64];   // 16 KB
    __shared__ __align__(16) uint16_t Bs[128 * 64];   // 16 KB

    const int t    = threadIdx.x;
    const int w    = t >> 6;
    const int lane = t & 63;
    const int ln   = lane & 15;
    const int quad = lane >> 4;
    const int wr   = w >> 1;
    const int wc   = w & 1;

    f32x4 acc[4][4];
    const f32x4 z4 = {0.f, 0.f, 0.f, 0.f};
#pragma unroll
    for (int i = 0; i < 4; ++i)
#pragma unroll
        for (int j = 0; j < 4; ++j) acc[i][j] = z4;

    const char* Ag = (const char*)(A  + (size_t)m0 * E_);
    const char* Bg = (const char*)(Bw + (size_t)n0 * E_);
    const int rsub = lane >> 3;                         // 0..7
    const int colb = ((lane & 7) ^ rsub) * 16;          // swizzled source chunk

    for (int kk = 0; kk < E_; kk += 64) {
#pragma unroll
        for (int c = 0; c < 4; ++c) {
            glds16(Ag + (size_t)(c * 32 + w * 8 + rsub) * 2048 + kk * 2 + colb,
                   (char*)As + c * 4096 + w * 1024);
            glds16(Bg + (size_t)(c * 32 + w * 8 + rsub) * 2048 + kk * 2 + colb,
                   (char*)Bs + c * 4096 + w * 1024);
        }
        __syncthreads();

#pragma unroll
        for (int ks = 0; ks < 2; ++ks) {
            bf16x8 af[4], bf[4];
#pragma unroll
            for (int mt = 0; mt < 4; ++mt)
                af[mt] = *(const bf16x8*)&As[(wr * 64 + mt * 16 + ln) * 64 +
                                             (((ks * 4 + quad) ^ (ln & 7)) * 8)];
#pragma unroll
            for (int nt = 0; nt < 4; ++nt)
                bf[nt] = *(const bf16x8*)&Bs[(wc * 64 + nt * 16 + ln) * 64 +
                                             (((ks * 4 + quad) ^ (ln & 7)) * 8)];
#pragma unroll
            for (int mt = 0; mt < 4; ++mt)
#pragma unroll
                for (int nt = 0; nt < 4; ++nt)
                    acc[mt][nt] = __builtin_amdgcn_mfma_f32_16x16x32_bf16(
                        af[mt], bf[nt], acc[mt][nt], 0, 0, 0);
        }
        __syncthreads();
    }

    // epilogue; C/D layout: row = quad*4 + r, col = ln
#pragma unroll
    for (int mt = 0; mt < 4; ++mt) {
        const int rowb = m0 + wr * 64 + mt * 16 + quad * 4;
#pragma unroll
        for (int nt = 0; nt < 4; ++nt) {
            const int col = n0 + wc * 64 + nt * 16 + ln;
            const float bsum = bias[col];
            if (mode == 2) {
                int bb = rowb >> 11, s0 = rowb & 2047, hh = col >> 6, d = col & 63;
                float v0 = acc[mt][nt][0] + bsum, v1 = acc[mt][nt][1] + bsum;
                float v2 = acc[mt][nt][2] + bsum, v3 = acc[mt][nt][3] + bsum;
                uint2 o; o.x = pack2(v0, v1); o.y = pack2(v2, v3);
                *(uint2*)((uint16_t*)out + (((size_t)bb * H_ + hh) * DH_ + d) * S_ + s0) = o;
            } else {
#pragma unroll
                for (int r = 0; r < 4; ++r) {
                    float vv = (acc[mt][nt][r] + bsum) * scale;
                    int rr = rowb + r;
                    if (mode == 1) {
                        int bb = rr >> 11, s = rr & 2047, hh = col >> 6, d = col & 63;
                        ((uint16_t*)out)[(((size_t)bb * H_ + hh) * S_ + s) * DH_ + d] = f2bf(vv);
                    } else {
                        ((float*)out)[(size_t)rr * E_ + col] = vv;
                    }
                }
            }
        }
    }
}

// ---------------------------------------------------------------------------
// Kernel 3: flash attention, n-split waves, BARRIER-FREE main loop.
// Block = 64 q-rows of one (b,h). 4 waves; wave w owns K-columns
// [w*32, w*32+32) of each 128-wide tile (16 tiles). All MFMA fragments load
// DIRECTLY from global (L2-resident via XCD swizzle); the only main-loop LDS
// is the wave-private P buffer (lgkmcnt-ordered, no barrier).
//
// Occupancy fix (R3): epilogue O-reduction is chunked by nt (4 rounds x
// 13 KB reusing the P region) so LDS = 19456 B, and __launch_bounds__(256,4)
// -> 4 blocks/CU (16 waves) instead of 2.  Mask words come from the
// transposed layout (see mask_bits_kernel): 4 dwordx4 per iteration.
//
// Lane j-adjacency: kf[..][0] holds j=2*ln, kf[..][1] j=2*ln+1 -> score
// halves are adjacent columns -> one v_cvt_pk_bf16_f32 + ds_write_b32.
// No-max softmax (exp2 safe: q pre-scaled by log2e/8); l deferred; partial
// O reduced across waves once at the end.
// ---------------------------------------------------------------------------
__global__ __launch_bounds__(256, 4)
void attn_kernel(const uint16_t* __restrict__ qb, const uint16_t* __restrict__ kb,
                 const uint16_t* __restrict__ vtb, const uint32_t* __restrict__ mbits,
                 uint16_t* __restrict__ attn_out) {
    // XCD-aware decode of flat block id: xcd = wg%8 = bh%8
    const int wg   = blockIdx.x;
    const int xcd  = wg & 7;
    const int rest = wg >> 3;
    const int qt   = rest & 31;                 // 0..31
    const int bh   = ((rest >> 5) << 3) | xcd;  // 0..63
    const int b    = bh >> 4, h = bh & 15;

    __shared__ __align__(16) char smem[19456];
    uint16_t* p_all = (uint16_t*)smem;          // 4 waves * 64 rows * 36 u16 = 18432 B

    const int t    = threadIdx.x;
    const int w    = t >> 6;
    const int lane = t & 63;
    const int ln   = lane & 15;
    const int quad = lane >> 4;
    const int ln2  = ln << 1;

    const char* qg  = (const char*)(qb  + ((size_t)bh * S_ + qt * 64) * DH_);
    const char* kg  = (const char*)(kb  + (size_t)bh * S_ * DH_);
    const char* vtg = (const char*)(vtb + (size_t)bh * DH_ * S_);

    // ---- Q A-frags direct from global (row mt*16+ln, chunk ks*32+quad*8)
    bf16x8 aq[4][2];
#pragma unroll
    for (int mt = 0; mt < 4; ++mt)
#pragma unroll
        for (int ks = 0; ks < 2; ++ks)
            aq[mt][ks] = *(const bf16x8*)(qg + (size_t)(mt * 16 + ln) * 128 +
                                          ks * 64 + quad * 16);

    f32x4 acc_o[4][4];
    const f32x4 z4 = {0.f, 0.f, 0.f, 0.f};
#pragma unroll
    for (int mt = 0; mt < 4; ++mt)
#pragma unroll
        for (int nt = 0; nt < 4; ++nt) acc_o[mt][nt] = z4;
    float lr[4][4];
#pragma unroll
    for (int mt = 0; mt < 4; ++mt)
#pragma unroll
        for (int r = 0; r < 4; ++r) lr[mt][r] = 0.f;

    uint16_t* pw = p_all + w * 2304;    // 64 rows * 36 u16, wave-private

    // per-lane streaming pointers
    const char* kp0 = kg + (size_t)(w * 32 + ln2) * 128 + quad * 16;       // j = 2*ln
    const char* kp1 = kg + (size_t)(w * 32 + ln2 + 1) * 128 + quad * 16;   // j = 2*ln+1
    const char* vp  = vtg + (size_t)ln * 4096 + w * 64 + quad * 16;        // d row = ln (+nt*16)
    // transposed mask base: [(b*32+qt)*4 + w] block of 1024 u32
    const uint32_t* mw = mbits + (((size_t)(b * 32 + qt) * 4 + w) << 10);

    // ---- prefetch K frags for it=0  (kf[ks][half])
    bf16x8 kf[2][2];
#pragma unroll
    for (int ks = 0; ks < 2; ++ks) {
        kf[ks][0] = *(const bf16x8*)(kp0 + ks * 64);
        kf[ks][1] = *(const bf16x8*)(kp1 + ks * 64);
    }

    for (int it = 0; it < 16; ++it) {
        // ---- V^T frags for current tile (used after exp -> long latency slack)
        bf16x8 bv[4];
#pragma unroll
        for (int nt = 0; nt < 4; ++nt)
            bv[nt] = *(const bf16x8*)(vp + (size_t)nt * 65536);
        // ---- mask words for current tile: 4 x dwordx4 (broadcast per quad)
        uint4 mk4[4];
#pragma unroll
        for (int mt = 0; mt < 4; ++mt)
            mk4[mt] = *(const uint4*)(mw + it * 64 + quad * 16 + mt * 4);
        // ---- K frags for NEXT tile (workspace has live regions past kproj,
        //      so the it=15 over-read is harmless)
        bf16x8 kn[2][2];
#pragma unroll
        for (int ks = 0; ks < 2; ++ks) {
            kn[ks][0] = *(const bf16x8*)(kp0 + 16384 + ks * 64);
            kn[ks][1] = *(const bf16x8*)(kp1 + 16384 + ks * 64);
        }

        // ---- scores over wave's 32-col strip: 16 MFMAs (kf already resident)
        // sc[mt][0][r] -> column 2*ln (even), sc[mt][1][r] -> 2*ln+1 (odd)
        f32x4 sc[4][2];
#pragma unroll
        for (int mt = 0; mt < 4; ++mt) { sc[mt][0] = z4; sc[mt][1] = z4; }
#pragma unroll
        for (int ks = 0; ks < 2; ++ks)
#pragma unroll
            for (int mt = 0; mt < 4; ++mt) {
                sc[mt][0] = __builtin_amdgcn_mfma_f32_16x16x32_bf16(aq[mt][ks], kf[ks][0], sc[mt][0], 0, 0, 0);
                sc[mt][1] = __builtin_amdgcn_mfma_f32_16x16x32_bf16(aq[mt][ks], kf[ks][1], sc[mt][1], 0, 0, 0);
            }

        // ---- exp2 + mask + partial l + packed P write (no max subtraction)
#pragma unroll
        for (int mt = 0; mt < 4; ++mt) {
            const uint32_t* mkp = (const uint32_t*)&mk4[mt];
#pragma unroll
            for (int r = 0; r < 4; ++r) {
                uint32_t sh = mkp[r] >> ln2;
                float e0 = (sh & 1u) ? 0.f : exp2_fast(sc[mt][0][r]);
                float e1 = (sh & 2u) ? 0.f : exp2_fast(sc[mt][1][r]);
                lr[mt][r] += e0 + e1;
                *(uint32_t*)&pw[(mt * 16 + quad * 4 + r) * 36 + ln2] = cvt_pk_bf16(e0, e1);
            }
        }
        // no barrier: pw is wave-private (lgkmcnt orders write->read)

        // ---- PV: O[q][d] += P[q][j] * V^T[d][j], 16 MFMAs
#pragma unroll
        for (int mt = 0; mt < 4; ++mt) {
            bf16x4 lo = *(const bf16x4*)&pw[(mt * 16 + ln) * 36 + quad * 8];
            bf16x4 hi = *(const bf16x4*)&pw[(mt * 16 + ln) * 36 + quad * 8 + 4];
            bf16x8 ap = __builtin_shufflevector(lo, hi, 0, 1, 2, 3, 4, 5, 6, 7);
#pragma unroll
            for (int nt = 0; nt < 4; ++nt)
                acc_o[mt][nt] = __builtin_amdgcn_mfma_f32_16x16x32_bf16(ap, bv[nt], acc_o[mt][nt], 0, 0, 0);
        }

        // ---- rotate K double-buffer, advance pointers
#pragma unroll
        for (int ks = 0; ks < 2; ++ks) {
            kf[ks][0] = kn[ks][0];
            kf[ks][1] = kn[ks][1];
        }
        kp0 += 16384; kp1 += 16384; vp += 256;
    }

    // ---- reduce l within wave (over ln; each lane holds 2 adjacent cols)
#pragma unroll
    for (int mt = 0; mt < 4; ++mt)
#pragma unroll
        for (int r = 0; r < 4; ++r) {
            float v = lr[mt][r];
            v += __shfl_xor(v, 1);
            v += __shfl_xor(v, 2);
            v += __shfl_xor(v, 4);
            v += __shfl_xor(v, 8);
            lr[mt][r] = v;
        }

    // ---- publish l partials (lbuf is outside the P region)
    float* obuf = (float*)smem;                 // 12 regions x [16][17] f32 = 13056 B
    float* lbuf = (float*)(smem + 18432);       // 4 x 64 f32 = 1024 B
    if (ln == 0) {
#pragma unroll
        for (int mt = 0; mt < 4; ++mt)
#pragma unroll
            for (int r = 0; r < 4; ++r)
                lbuf[w * 64 + mt * 16 + quad * 4 + r] = lr[mt][r];
    }
    __syncthreads();   // all waves done with P region + lbuf visible

    float invl[4];
#pragma unroll
    for (int rr = 0; rr < 4; ++rr) {
        int row = w * 16 + quad * 4 + rr;
        float lt = lbuf[row] + lbuf[64 + row] + lbuf[128 + row] + lbuf[192 + row];
        invl[rr] = 1.0f / lt;
    }

    const size_t orow = (size_t)(b * S_ + qt * 64 + w * 16 + quad * 4);
    // ---- chunked cross-wave O reduction: one nt (16 d-cols) at a time
#pragma unroll
    for (int nt = 0; nt < 4; ++nt) {
        // write partials for non-owned q-tiles
#pragma unroll
        for (int mt = 0; mt < 4; ++mt) {
            if (mt != w) {
                int ridx = mt * 3 + (w > mt ? w - 1 : w);
                float* reg = obuf + ridx * 272;   // [16][17]
#pragma unroll
                for (int rr = 0; rr < 4; ++rr)
                    reg[(quad * 4 + rr) * 17 + ln] = acc_o[mt][nt][rr];
            }
        }
        __syncthreads();
        // own tile (mt == w), accumulate the 3 partials
        f32x4 af = acc_o[0][nt];
        if (w == 1) af = acc_o[1][nt];
        else if (w == 2) af = acc_o[2][nt];
        else if (w == 3) af = acc_o[3][nt];
#pragma unroll
        for (int widx = 0; widx < 3; ++widx) {
            const float* reg = obuf + (w * 3 + widx) * 272;
#pragma unroll
            for (int rr = 0; rr < 4; ++rr)
                af[rr] += reg[(quad * 4 + rr) * 17 + ln];
        }
#pragma unroll
        for (int rr = 0; rr < 4; ++rr)
            attn_out[(orow + rr) * E_ + h * 64 + nt * 16 + ln] = f2bf(af[rr] * invl[rr]);
        if (nt != 3) __syncthreads();   // before next chunk overwrites obuf
    }
}

// ---------------------------------------------------------------------------
// Launcher.  Workspace layout (MB):
//   [0,8)    Wq,Wk,Wv,Wo bf16
//   [8,24)   query bf16    [24,40) key bf16    [40,56) value bf16
//   [56,72)  q proj bf16 [B,H,S,Dh] (scaled log2e/8)
//   [72,88)  k proj bf16 [B,H,S,Dh]
//   [88,104) v proj bf16 [B,H,Dh,S] (transposed)
//   [104,120) attn out bf16 [B*S, E]
//   [120,122) mask bitmask (transposed layout, 2 MB)
// ---------------------------------------------------------------------------
extern "C" void kernel_launch(void* const* d_in, const int* in_sizes, int n_in,
                              void* d_out, int out_size, void* d_ws, size_t ws_size,
                              hipStream_t stream) {
    const float* query = (const float*)d_in[0];
    const float* key_  = (const float*)d_in[1];
    const float* value = (const float*)d_in[2];
    const int*   mask  = (const int*)d_in[3];
    const float* Wq = (const float*)d_in[4];
    const float* bq = (const float*)d_in[5];
    const float* Wk = (const float*)d_in[6];
    const float* bk = (const float*)d_in[7];
    const float* Wv = (const float*)d_in[8];
    const float* bv = (const float*)d_in[9];
    const float* Wo = (const float*)d_in[10];
    const float* bo = (const float*)d_in[11];

    char* ws = (char*)d_ws;
    uint16_t* wbf   = (uint16_t*)ws;
    uint16_t* qa    = (uint16_t*)(ws + (8u   << 20));
    uint16_t* ka    = (uint16_t*)(ws + (24u  << 20));
    uint16_t* va    = (uint16_t*)(ws + (40u  << 20));
    uint16_t* qproj = (uint16_t*)(ws + (56u  << 20));
    uint16_t* kproj = (uint16_t*)(ws + (72u  << 20));
    uint16_t* vtp   = (uint16_t*)(ws + (88u  << 20));
    uint16_t* atto  = (uint16_t*)(ws + (104u << 20));
    uint32_t* mbits = (uint32_t*)(ws + (120u << 20));

    prep_kernel<<<14336, 256, 0, stream>>>(query, key_, value, Wq, Wk, Wv, Wo,
                                           wbf, qa, ka, va);
    mask_bits_kernel<<<65536, 256, 0, stream>>>(mask, mbits);

    // q/k/v projections in one launch (z selects input/weight/output)
    gemm_bt_kernel<<<dim3(E_ / 128, M_ / 128, 3), 256, 0, stream>>>(
        qa, ka, va, wbf, bq, bk, bv, qproj, kproj, vtp, 1);

    attn_kernel<<<dim3(2048), 256, 0, stream>>>(
        qproj, kproj, vtp, mbits, atto);

    // final projection: A=atto, W=Wo (4th weight), fp32 out
    gemm_bt_kernel<<<dim3(E_ / 128, M_ / 128, 1), 256, 0, stream>>>(
        atto, atto, atto, wbf + 3145728, bo, bo, bo, d_out, d_out, d_out, 0);
}

// Round 4
// 429.578 us; speedup vs baseline: 1.8842x; 1.8842x over previous
//
#include <hip/hip_runtime.h>
#include <cstdint>

// Problem constants
#define B_  4
#define H_  16
#define S_  2048
#define DH_ 64
#define E_  1024
#define M_  (B_ * S_)   // 8192 rows for all projection GEMMs

typedef __attribute__((ext_vector_type(8))) __bf16 bf16x8;
typedef __attribute__((ext_vector_type(4))) __bf16 bf16x4;
typedef __attribute__((ext_vector_type(4))) float  f32x4;

// fp32 -> bf16 (round-to-nearest-even), bit-level
__device__ __forceinline__ uint16_t f2bf(float f) {
    union { float f; uint32_t u; } v; v.f = f;
    uint32_t u = v.u;
    uint32_t r = (u + 0x7fffu + ((u >> 16) & 1u)) >> 16;
    return (uint16_t)r;
}
__device__ __forceinline__ uint32_t pack2(float a, float b) {
    return (uint32_t)f2bf(a) | ((uint32_t)f2bf(b) << 16);
}

// hardware packed fp32->bf16 (RNE), 2 values -> 1 dword.  lo in [15:0].
__device__ __forceinline__ uint32_t cvt_pk_bf16(float lo, float hi) {
    uint32_t r;
    asm("v_cvt_pk_bf16_f32 %0, %1, %2" : "=v"(r) : "v"(lo), "v"(hi));
    return r;
}

// 2^x directly on the trans pipe (v_exp_f32 computes 2^S0)
__device__ __forceinline__ float exp2_fast(float x) {
#if __has_builtin(__builtin_amdgcn_exp2f)
    return __builtin_amdgcn_exp2f(x);
#else
    float r; asm("v_exp_f32 %0, %1" : "=v"(r) : "v"(x)); return r;
#endif
}

// async global->LDS, 16B per lane. LDS dest is wave-uniform base; HW adds lane*16.
__device__ __forceinline__ void glds16(const void* g, void* lds_base) {
    __builtin_amdgcn_global_load_lds(
        (const __attribute__((address_space(1))) uint32_t*)g,
        (__attribute__((address_space(3))) uint32_t*)lds_base, 16, 0, 0);
}

// ---------------------------------------------------------------------------
// Kernel 1 (fused prep): cast Wq/Wk/Wv/Wo and query/key/value fp32 -> bf16.
// ---------------------------------------------------------------------------
__global__ void prep_kernel(const float* __restrict__ q, const float* __restrict__ k,
                            const float* __restrict__ v,
                            const float* __restrict__ w0, const float* __restrict__ w1,
                            const float* __restrict__ w2, const float* __restrict__ w3,
                            uint16_t* __restrict__ wbf,
                            uint16_t* __restrict__ qa, uint16_t* __restrict__ ka,
                            uint16_t* __restrict__ va) {
    int bid = blockIdx.x;
    const float* src; uint16_t* dst; int base;
    if (bid < 2048) {
        int i = bid * 256 + threadIdx.x;
        base = i * 8;                         // [0, 4*2^20)
        int wsel = base >> 20;
        src = (wsel == 0) ? w0 : (wsel == 1) ? w1 : (wsel == 2) ? w2 : w3;
        dst = wbf + base;
        base &= 1048575;
    } else {
        int r = bid - 2048;                   // [0, 12288)
        int sel = r >> 12;                    // 4096 blocks per activation
        int i = (r & 4095) * 256 + threadIdx.x;
        base = i * 8;                         // [0, 2^23)
        src = (sel == 0) ? q : (sel == 1) ? k : v;
        dst = ((sel == 0) ? qa : (sel == 1) ? ka : va) + base;
    }
    float4 a = *(const float4*)(src + base);
    float4 b = *(const float4*)(src + base + 4);
    uint4 o;
    o.x = pack2(a.x, a.y); o.y = pack2(a.z, a.w);
    o.z = pack2(b.x, b.y); o.w = pack2(b.z, b.w);
    *(uint4*)dst = o;
}

// ---------------------------------------------------------------------------
// Mask int32 -> bitmask in the transposed layout for the 256-row-block attn:
// word (b,row,c) covers cols [c*32,+32).  Decompose row = qt8*256 + w*64 +
// mt*16 + quad*4 + r, c = it*4 + js.  Word index:
//   (((((b*8+qt8)*4 + w)*4 + js)*16 + it)*4 + quad)*4 + mt)*4 + r
// -> attn lane fetches its 16 words per (it,js) as 4 x dwordx4 over mt.
// bit=1 -> masked.
// ---------------------------------------------------------------------------
__global__ void mask_bits_kernel(const int* __restrict__ mask, uint32_t* __restrict__ bits) {
    int idx = blockIdx.x * 256 + threadIdx.x;      // element in [B*S*S)
    uint64_t bl = __ballot(mask[idx] != 0);        // 64 consecutive cols of one row
    if ((threadIdx.x & 63) == 0) {
        int col  = idx & 2047;                     // base col of this wave
        int row  = (idx >> 11) & 2047;
        int b    = idx >> 22;
        int qt8  = row >> 8;
        int rw   = row & 255;
        int w    = rw >> 6, sl = rw & 63;
        int mt   = sl >> 4, quad = (sl >> 2) & 3, r = sl & 3;
        int c0   = col >> 5;                       // even word index
#pragma unroll
        for (int half = 0; half < 2; ++half) {
            int c  = c0 + half;
            int it = c >> 2, js = c & 3;
            size_t i = (((((((size_t)(b * 8 + qt8) * 4 + w) * 4 + js) * 16 + it)
                          * 4 + quad) * 4 + mt) * 4 + r);
            bits[i] = (uint32_t)(half ? (bl >> 32) : bl);
        }
    }
}

// ---------------------------------------------------------------------------
// Kernel 2: C = A @ W^T + bias GEMM, bf16 in, global_load_lds staging with
// XOR-chunk swizzle (phys_chunk = chunk ^ (row&7)) so frag reads are <=2-way.
//   mode 0: fp32 out [8192,1024]
//   mode 1: bf16 out scattered to [B,H,S,Dh]
//   mode 2: bf16 out scattered to [B,H,Dh,S] (V transposed)
// q is scaled by 0.125*log2(e) so attention can use exp2 directly.
// ---------------------------------------------------------------------------
__global__ __launch_bounds__(256, 2)
void gemm_bt_kernel(const uint16_t* __restrict__ A0, const uint16_t* __restrict__ A1,
                    const uint16_t* __restrict__ A2,
                    const uint16_t* __restrict__ Bw0,
                    const float* __restrict__ bias0, const float* __restrict__ bias1,
                    const float* __restrict__ bias2,
                    void* __restrict__ out0, void* __restrict__ out1,
                    void* __restrict__ out2,
                    int multi) {
    const int z = blockIdx.z;
    const uint16_t* A  = (z == 0) ? A0 : (z == 1) ? A1 : A2;
    const uint16_t* Bw = Bw0 + (size_t)z * 1048576;
    const float* bias  = (z == 0) ? bias0 : (z == 1) ? bias1 : bias2;
    void* out          = (z == 0) ? out0 : (z == 1) ? out1 : out2;
    const float scale  = (multi && z == 0) ? 0.18033688f : 1.0f;  // 0.125*log2e
    const int mode     = multi ? ((z == 2) ? 2 : 1) : 0;

    const int m0 = blockIdx.y * 128;
    const int n0 = blockIdx.x * 128;

    __shared__ __align__(16) uint16_t As[128 * 64];   // 16 KB
    __shared__ __align__(16) uint16_t Bs[128 * 64];   // 16 KB

    const int t    = threadIdx.x;
    const int w    = t >> 6;
    const int lane = t & 63;
    const int ln   = lane & 15;
    const int quad = lane >> 4;
    const int wr   = w >> 1;
    const int wc   = w & 1;

    f32x4 acc[4][4];
    const f32x4 z4 = {0.f, 0.f, 0.f, 0.f};
#pragma unroll
    for (int i = 0; i < 4; ++i)
#pragma unroll
        for (int j = 0; j < 4; ++j) acc[i][j] = z4;

    const char* Ag = (const char*)(A  + (size_t)m0 * E_);
    const char* Bg = (const char*)(Bw + (size_t)n0 * E_);
    const int rsub = lane >> 3;                         // 0..7
    const int colb = ((lane & 7) ^ rsub) * 16;          // swizzled source chunk

    for (int kk = 0; kk < E_; kk += 64) {
#pragma unroll
        for (int c = 0; c < 4; ++c) {
            glds16(Ag + (size_t)(c * 32 + w * 8 + rsub) * 2048 + kk * 2 + colb,
                   (char*)As + c * 4096 + w * 1024);
            glds16(Bg + (size_t)(c * 32 + w * 8 + rsub) * 2048 + kk * 2 + colb,
                   (char*)Bs + c * 4096 + w * 1024);
        }
        __syncthreads();

#pragma unroll
        for (int ks = 0; ks < 2; ++ks) {
            bf16x8 af[4], bf[4];
#pragma unroll
            for (int mt = 0; mt < 4; ++mt)
                af[mt] = *(const bf16x8*)&As[(wr * 64 + mt * 16 + ln) * 64 +
                                             (((ks * 4 + quad) ^ (ln & 7)) * 8)];
#pragma unroll
            for (int nt = 0; nt < 4; ++nt)
                bf[nt] = *(const bf16x8*)&Bs[(wc * 64 + nt * 16 + ln) * 64 +
                                             (((ks * 4 + quad) ^ (ln & 7)) * 8)];
#pragma unroll
            for (int mt = 0; mt < 4; ++mt)
#pragma unroll
                for (int nt = 0; nt < 4; ++nt)
                    acc[mt][nt] = __builtin_amdgcn_mfma_f32_16x16x32_bf16(
                        af[mt], bf[nt], acc[mt][nt], 0, 0, 0);
        }
        __syncthreads();
    }

    // epilogue; C/D layout: row = quad*4 + r, col = ln
#pragma unroll
    for (int mt = 0; mt < 4; ++mt) {
        const int rowb = m0 + wr * 64 + mt * 16 + quad * 4;
#pragma unroll
        for (int nt = 0; nt < 4; ++nt) {
            const int col = n0 + wc * 64 + nt * 16 + ln;
            const float bsum = bias[col];
            if (mode == 2) {
                int bb = rowb >> 11, s0 = rowb & 2047, hh = col >> 6, d = col & 63;
                float v0 = acc[mt][nt][0] + bsum, v1 = acc[mt][nt][1] + bsum;
                float v2 = acc[mt][nt][2] + bsum, v3 = acc[mt][nt][3] + bsum;
                uint2 o; o.x = pack2(v0, v1); o.y = pack2(v2, v3);
                *(uint2*)((uint16_t*)out + (((size_t)bb * H_ + hh) * DH_ + d) * S_ + s0) = o;
            } else {
#pragma unroll
                for (int r = 0; r < 4; ++r) {
                    float vv = (acc[mt][nt][r] + bsum) * scale;
                    int rr = rowb + r;
                    if (mode == 1) {
                        int bb = rr >> 11, s = rr & 2047, hh = col >> 6, d = col & 63;
                        ((uint16_t*)out)[(((size_t)bb * H_ + hh) * S_ + s) * DH_ + d] = f2bf(vv);
                    } else {
                        ((float*)out)[(size_t)rr * E_ + col] = vv;
                    }
                }
            }
        }
    }
}

// ---------------------------------------------------------------------------
// Kernel 3: flash attention, 256-row Q-blocks, m-split waves.
// Block = 256 q-rows of one (b,h); wave w owns rows [w*64, +64).  Per K-tile
// (128 j): K (128x64, even/odd row interleave + XOR chunk swizzle) and V^T
// (64x128, chunk^row swizzle) staged to LDS via glds16 and shared by ALL 4
// waves (real reuse: K/V read 8x per bh instead of 32x -> 4x less L2
// traffic/transactions than the 64-row n-split).  Each wave then processes 4
// j-substrips of 32: 16 score MFMAs -> exp2+mask+pack -> 16 PV MFMAs.
//
// No cross-wave O reduction: each wave owns its rows; l reduced by in-wave
// shfl; direct store with 1/l scaling.  P buffer is wave-private LDS
// (lgkmcnt-ordered, no extra barriers).  2 barriers per tile (stage/consume).
//
// Even/odd j-interleave: strip row p holds j = (p<16 ? 2p : 2p-31), so the
// two score MFMAs of a lane give adjacent cols 2*ln, 2*ln+1 -> one
// v_cvt_pk_bf16_f32 + ds_write_b32.  No-max softmax (q pre-scaled log2e/8).
//
// Grid 512 = 8 qt-blocks x 64 bh, XCD swizzle: each XCD runs 8 bh's x 8
// qt-blocks -> 4 MB K/V working set = one XCD L2.
// Registers: aq 32 + acc_o 64 + sc 32 + frags/masks ~50 => ~210, fits
// launch_bounds(256,2) cap 256 with NO spill (R3 lesson: do this arithmetic).
// ---------------------------------------------------------------------------
__global__ __launch_bounds__(256, 2)
void attn_kernel(const uint16_t* __restrict__ qb, const uint16_t* __restrict__ kb,
                 const uint16_t* __restrict__ vtb, const uint32_t* __restrict__ mbits,
                 uint16_t* __restrict__ attn_out) {
    const int wg   = blockIdx.x;                // 0..511
    const int xcd  = wg & 7;
    const int rest = wg >> 3;                   // 0..63
    const int qt8  = rest & 7;                  // 256-row q block
    const int bh   = ((rest >> 3) << 3) | xcd;  // 0..63
    const int b    = bh >> 4, h = bh & 15;

    __shared__ __align__(16) char smem[51200];
    uint16_t* k_lds  = (uint16_t*)smem;                 // 128*64 u16 = 16 KB
    uint16_t* vt_lds = (uint16_t*)(smem + 16384);       // 64*128 u16 = 16 KB
    uint16_t* p_all  = (uint16_t*)(smem + 32768);       // 4*64*36 u16 = 18432 B

    const int t    = threadIdx.x;
    const int w    = t >> 6;
    const int lane = t & 63;
    const int ln   = lane & 15;
    const int quad = lane >> 4;
    const int ln2  = ln << 1;

    const char* qg  = (const char*)(qb  + ((size_t)bh * S_ + qt8 * 256) * DH_);
    const char* kg  = (const char*)(kb  + (size_t)bh * S_ * DH_);
    const char* vtg = (const char*)(vtb + (size_t)bh * DH_ * S_);

    // ---- Q A-frags direct from global: wave's own 64 rows
    bf16x8 aq[4][2];
#pragma unroll
    for (int mt = 0; mt < 4; ++mt)
#pragma unroll
        for (int ks = 0; ks < 2; ++ks)
            aq[mt][ks] = *(const bf16x8*)(qg + (size_t)(w * 64 + mt * 16 + ln) * 128 +
                                          ks * 64 + quad * 16);

    f32x4 acc_o[4][4];
    const f32x4 z4 = {0.f, 0.f, 0.f, 0.f};
#pragma unroll
    for (int mt = 0; mt < 4; ++mt)
#pragma unroll
        for (int nt = 0; nt < 4; ++nt) acc_o[mt][nt] = z4;
    float lr[4][4];
#pragma unroll
    for (int mt = 0; mt < 4; ++mt)
#pragma unroll
        for (int r = 0; r < 4; ++r) lr[mt][r] = 0.f;

    uint16_t* pw = p_all + w * 2304;            // 64 rows * 36 u16, wave-private
    // transposed mask base for this (b,qt8,wave,quad)
    const uint32_t* mw = mbits + (size_t)(b * 8 + qt8) * 16384 + w * 4096 + quad * 16;

    const int rsub = lane >> 3;                 // 0..7
    const int kcol = ((lane & 7) ^ rsub) * 16;  // swizzled source chunk (K)

    for (int it = 0; it < 16; ++it) {
        // ---- stage K tile (128x64): wave w stages strip rows [w*32,+32)
        //      with even/odd interleave; 4 glds/wave
        const char* kt = kg + (size_t)it * 16384;
#pragma unroll
        for (int c = 0; c < 4; ++c) {
            const int p    = c * 8 + rsub;                      // 0..31
            const int jrow = (p < 16) ? (2 * p) : (2 * p - 31); // even/odd perm
            glds16(kt + (size_t)(w * 32 + jrow) * 128 + kcol,
                   (char*)k_lds + w * 4096 + c * 1024);
        }
        // ---- stage V^T tile (64 d-rows x 128 j, chunk^row swizzle): 4 glds/wave
#pragma unroll
        for (int c = 0; c < 4; ++c) {
            int d0  = w * 16 + c * 4;
            int row = d0 + (lane >> 4);
            int gch = (lane & 15) ^ (row & 15);
            glds16(vtg + (size_t)row * (S_ * 2) + it * 256 + gch * 16,
                   (char*)vt_lds + d0 * 256);
        }
        __syncthreads();

        // ---- 4 substrips of 32 j each
#pragma unroll
        for (int js = 0; js < 4; ++js) {
            // mask words: 4 x dwordx4 (r innermost), broadcast within quad
            uint4 mk4[4];
#pragma unroll
            for (int mt = 0; mt < 4; ++mt)
                mk4[mt] = *(const uint4*)(mw + js * 1024 + it * 64 + mt * 4);
            // V^T B-frags for this substrip
            bf16x8 bv[4];
#pragma unroll
            for (int nt = 0; nt < 4; ++nt)
                bv[nt] = *(const bf16x8*)&vt_lds[(nt * 16 + ln) * 128 +
                                                 (((js * 4 + quad) ^ ln) * 8)];

            // scores: 64 q-rows x 32 j, 16 MFMAs
            f32x4 sc[4][2];
#pragma unroll
            for (int mt = 0; mt < 4; ++mt) { sc[mt][0] = z4; sc[mt][1] = z4; }
#pragma unroll
            for (int ks = 0; ks < 2; ++ks) {
                bf16x8 bk0 = *(const bf16x8*)&k_lds[(js * 32 + ln) * 64 +
                                                    (((ks * 4 + quad) ^ (ln & 7)) * 8)];
                bf16x8 bk1 = *(const bf16x8*)&k_lds[(js * 32 + 16 + ln) * 64 +
                                                    (((ks * 4 + quad) ^ (ln & 7)) * 8)];
#pragma unroll
                for (int mt = 0; mt < 4; ++mt) {
                    sc[mt][0] = __builtin_amdgcn_mfma_f32_16x16x32_bf16(aq[mt][ks], bk0, sc[mt][0], 0, 0, 0);
                    sc[mt][1] = __builtin_amdgcn_mfma_f32_16x16x32_bf16(aq[mt][ks], bk1, sc[mt][1], 0, 0, 0);
                }
            }

            // exp2 + mask + partial l + packed P write
#pragma unroll
            for (int mt = 0; mt < 4; ++mt) {
                const uint32_t* mkp = (const uint32_t*)&mk4[mt];
#pragma unroll
                for (int r = 0; r < 4; ++r) {
                    uint32_t sh = mkp[r] >> ln2;
                    float e0 = (sh & 1u) ? 0.f : exp2_fast(sc[mt][0][r]);
                    float e1 = (sh & 2u) ? 0.f : exp2_fast(sc[mt][1][r]);
                    lr[mt][r] += e0 + e1;
                    *(uint32_t*)&pw[(mt * 16 + quad * 4 + r) * 36 + ln2] = cvt_pk_bf16(e0, e1);
                }
            }
            // no barrier: pw is wave-private (lgkmcnt orders write->read)

            // PV: O[q][d] += P[q][j] * V^T[d][j], 16 MFMAs
#pragma unroll
            for (int mt = 0; mt < 4; ++mt) {
                bf16x4 lo = *(const bf16x4*)&pw[(mt * 16 + ln) * 36 + quad * 8];
                bf16x4 hi = *(const bf16x4*)&pw[(mt * 16 + ln) * 36 + quad * 8 + 4];
                bf16x8 ap = __builtin_shufflevector(lo, hi, 0, 1, 2, 3, 4, 5, 6, 7);
#pragma unroll
                for (int nt = 0; nt < 4; ++nt)
                    acc_o[mt][nt] = __builtin_amdgcn_mfma_f32_16x16x32_bf16(ap, bv[nt], acc_o[mt][nt], 0, 0, 0);
            }
        }
        __syncthreads();   // protect k/vt before next tile's staging
    }

    // ---- reduce l within wave (sum over ln bits -> full 2048-col row sum)
    float invl[4][4];
#pragma unroll
    for (int mt = 0; mt < 4; ++mt)
#pragma unroll
        for (int r = 0; r < 4; ++r) {
            float v = lr[mt][r];
            v += __shfl_xor(v, 1);
            v += __shfl_xor(v, 2);
            v += __shfl_xor(v, 4);
            v += __shfl_xor(v, 8);
            invl[mt][r] = 1.0f / v;
        }

    // ---- direct store (wave owns its rows; no cross-wave reduction)
    const size_t orow0 = (size_t)b * S_ + qt8 * 256 + w * 64;
#pragma unroll
    for (int mt = 0; mt < 4; ++mt)
#pragma unroll
        for (int r = 0; r < 4; ++r) {
            const size_t row = orow0 + mt * 16 + quad * 4 + r;
#pragma unroll
            for (int nt = 0; nt < 4; ++nt)
                attn_out[row * E_ + h * 64 + nt * 16 + ln] =
                    f2bf(acc_o[mt][nt][r] * invl[mt][r]);
        }
}

// ---------------------------------------------------------------------------
// Launcher.  Workspace layout (MB):
//   [0,8)    Wq,Wk,Wv,Wo bf16
//   [8,24)   query bf16    [24,40) key bf16    [40,56) value bf16
//   [56,72)  q proj bf16 [B,H,S,Dh] (scaled log2e/8)
//   [72,88)  k proj bf16 [B,H,S,Dh]
//   [88,104) v proj bf16 [B,H,Dh,S] (transposed)
//   [104,120) attn out bf16 [B*S, E]
//   [120,122) mask bitmask (transposed layout, 2 MB)
// ---------------------------------------------------------------------------
extern "C" void kernel_launch(void* const* d_in, const int* in_sizes, int n_in,
                              void* d_out, int out_size, void* d_ws, size_t ws_size,
                              hipStream_t stream) {
    const float* query = (const float*)d_in[0];
    const float* key_  = (const float*)d_in[1];
    const float* value = (const float*)d_in[2];
    const int*   mask  = (const int*)d_in[3];
    const float* Wq = (const float*)d_in[4];
    const float* bq = (const float*)d_in[5];
    const float* Wk = (const float*)d_in[6];
    const float* bk = (const float*)d_in[7];
    const float* Wv = (const float*)d_in[8];
    const float* bv = (const float*)d_in[9];
    const float* Wo = (const float*)d_in[10];
    const float* bo = (const float*)d_in[11];

    char* ws = (char*)d_ws;
    uint16_t* wbf   = (uint16_t*)ws;
    uint16_t* qa    = (uint16_t*)(ws + (8u   << 20));
    uint16_t* ka    = (uint16_t*)(ws + (24u  << 20));
    uint16_t* va    = (uint16_t*)(ws + (40u  << 20));
    uint16_t* qproj = (uint16_t*)(ws + (56u  << 20));
    uint16_t* kproj = (uint16_t*)(ws + (72u  << 20));
    uint16_t* vtp   = (uint16_t*)(ws + (88u  << 20));
    uint16_t* atto  = (uint16_t*)(ws + (104u << 20));
    uint32_t* mbits = (uint32_t*)(ws + (120u << 20));

    prep_kernel<<<14336, 256, 0, stream>>>(query, key_, value, Wq, Wk, Wv, Wo,
                                           wbf, qa, ka, va);
    mask_bits_kernel<<<65536, 256, 0, stream>>>(mask, mbits);

    // q/k/v projections in one launch (z selects input/weight/output)
    gemm_bt_kernel<<<dim3(E_ / 128, M_ / 128, 3), 256, 0, stream>>>(
        qa, ka, va, wbf, bq, bk, bv, qproj, kproj, vtp, 1);

    attn_kernel<<<dim3(512), 256, 0, stream>>>(
        qproj, kproj, vtp, mbits, atto);

    // final projection: A=atto, W=Wo (4th weight), fp32 out
    gemm_bt_kernel<<<dim3(E_ / 128, M_ / 128, 1), 256, 0, stream>>>(
        atto, atto, atto, wbf + 3145728, bo, bo, bo, d_out, d_out, d_out, 0);
}

// Round 5
// 419.006 us; speedup vs baseline: 1.9317x; 1.0252x over previous
//
#include <hip/hip_runtime.h>
#include <cstdint>

// Problem constants
#define B_  4
#define H_  16
#define S_  2048
#define DH_ 64
#define E_  1024
#define M_  (B_ * S_)   // 8192 rows for all projection GEMMs

typedef __attribute__((ext_vector_type(8))) __bf16 bf16x8;
typedef __attribute__((ext_vector_type(4))) __bf16 bf16x4;
typedef __attribute__((ext_vector_type(4))) float  f32x4;

// fp32 -> bf16 (round-to-nearest-even), bit-level
__device__ __forceinline__ uint16_t f2bf(float f) {
    union { float f; uint32_t u; } v; v.f = f;
    uint32_t u = v.u;
    uint32_t r = (u + 0x7fffu + ((u >> 16) & 1u)) >> 16;
    return (uint16_t)r;
}
__device__ __forceinline__ uint32_t pack2(float a, float b) {
    return (uint32_t)f2bf(a) | ((uint32_t)f2bf(b) << 16);
}

// hardware packed fp32->bf16 (RNE), 2 values -> 1 dword.  lo in [15:0].
__device__ __forceinline__ uint32_t cvt_pk_bf16(float lo, float hi) {
    uint32_t r;
    asm("v_cvt_pk_bf16_f32 %0, %1, %2" : "=v"(r) : "v"(lo), "v"(hi));
    return r;
}

// 2^x directly on the trans pipe (v_exp_f32 computes 2^S0)
__device__ __forceinline__ float exp2_fast(float x) {
#if __has_builtin(__builtin_amdgcn_exp2f)
    return __builtin_amdgcn_exp2f(x);
#else
    float r; asm("v_exp_f32 %0, %1" : "=v"(r) : "v"(x)); return r;
#endif
}

// async global->LDS, 16B per lane. LDS dest is wave-uniform base; HW adds lane*16.
__device__ __forceinline__ void glds16(const void* g, void* lds_base) {
    __builtin_amdgcn_global_load_lds(
        (const __attribute__((address_space(1))) uint32_t*)g,
        (__attribute__((address_space(3))) uint32_t*)lds_base, 16, 0, 0);
}

// ---------------------------------------------------------------------------
// Kernel 1 (fused prep): cast Wq/Wk/Wv/Wo and query/key/value fp32 -> bf16.
// ---------------------------------------------------------------------------
__global__ void prep_kernel(const float* __restrict__ q, const float* __restrict__ k,
                            const float* __restrict__ v,
                            const float* __restrict__ w0, const float* __restrict__ w1,
                            const float* __restrict__ w2, const float* __restrict__ w3,
                            uint16_t* __restrict__ wbf,
                            uint16_t* __restrict__ qa, uint16_t* __restrict__ ka,
                            uint16_t* __restrict__ va) {
    int bid = blockIdx.x;
    const float* src; uint16_t* dst; int base;
    if (bid < 2048) {
        int i = bid * 256 + threadIdx.x;
        base = i * 8;                         // [0, 4*2^20)
        int wsel = base >> 20;
        src = (wsel == 0) ? w0 : (wsel == 1) ? w1 : (wsel == 2) ? w2 : w3;
        dst = wbf + base;
        base &= 1048575;
    } else {
        int r = bid - 2048;                   // [0, 12288)
        int sel = r >> 12;                    // 4096 blocks per activation
        int i = (r & 4095) * 256 + threadIdx.x;
        base = i * 8;                         // [0, 2^23)
        src = (sel == 0) ? q : (sel == 1) ? k : v;
        dst = ((sel == 0) ? qa : (sel == 1) ? ka : va) + base;
    }
    float4 a = *(const float4*)(src + base);
    float4 b = *(const float4*)(src + base + 4);
    uint4 o;
    o.x = pack2(a.x, a.y); o.y = pack2(a.z, a.w);
    o.z = pack2(b.x, b.y); o.w = pack2(b.z, b.w);
    *(uint4*)dst = o;
}

// ---------------------------------------------------------------------------
// Mask int32 -> bitmask in the transposed layout for the 256-row-block attn:
// word (b,row,c) covers cols [c*32,+32).  Decompose row = qt8*256 + w*64 +
// mt*16 + quad*4 + r, c = it*4 + js.  Word index:
//   (((((b*8+qt8)*4 + w)*4 + js)*16 + it)*4 + quad)*4 + mt)*4 + r
// -> attn lane fetches its 16 words per (it,js) as 4 x dwordx4 over mt.
// bit=1 -> masked.
// ---------------------------------------------------------------------------
__global__ void mask_bits_kernel(const int* __restrict__ mask, uint32_t* __restrict__ bits) {
    int idx = blockIdx.x * 256 + threadIdx.x;      // element in [B*S*S)
    uint64_t bl = __ballot(mask[idx] != 0);        // 64 consecutive cols of one row
    if ((threadIdx.x & 63) == 0) {
        int col  = idx & 2047;                     // base col of this wave
        int row  = (idx >> 11) & 2047;
        int b    = idx >> 22;
        int qt8  = row >> 8;
        int rw   = row & 255;
        int w    = rw >> 6, sl = rw & 63;
        int mt   = sl >> 4, quad = (sl >> 2) & 3, r = sl & 3;
        int c0   = col >> 5;                       // even word index
#pragma unroll
        for (int half = 0; half < 2; ++half) {
            int c  = c0 + half;
            int it = c >> 2, js = c & 3;
            size_t i = (((((((size_t)(b * 8 + qt8) * 4 + w) * 4 + js) * 16 + it)
                          * 4 + quad) * 4 + mt) * 4 + r);
            bits[i] = (uint32_t)(half ? (bl >> 32) : bl);
        }
    }
}

// ---------------------------------------------------------------------------
// Kernel 2: C = A @ W^T + bias GEMM, bf16 in, global_load_lds staging with
// XOR-chunk swizzle (phys_chunk = chunk ^ (row&7)) so frag reads are <=2-way.
//   mode 0: fp32 out [8192,1024]
//   mode 1: bf16 out scattered to [B,H,S,Dh]
//   mode 2: bf16 out scattered to [B,H,Dh,S] (V transposed)
// q is scaled by 0.125*log2(e) so attention can use exp2 directly.
// XCD-aware tile remap: XCD = (x+8y)%8; each XCD owns 8 consecutive m-tiles
// x all n-tiles -> A panels are read once from memory and 8x from own-XCD L2
// (was: 8 XCDs each fetching every A panel).
// ---------------------------------------------------------------------------
__global__ __launch_bounds__(256, 2)
void gemm_bt_kernel(const uint16_t* __restrict__ A0, const uint16_t* __restrict__ A1,
                    const uint16_t* __restrict__ A2,
                    const uint16_t* __restrict__ Bw0,
                    const float* __restrict__ bias0, const float* __restrict__ bias1,
                    const float* __restrict__ bias2,
                    void* __restrict__ out0, void* __restrict__ out1,
                    void* __restrict__ out2,
                    int multi) {
    const int z = blockIdx.z;
    const uint16_t* A  = (z == 0) ? A0 : (z == 1) ? A1 : A2;
    const uint16_t* Bw = Bw0 + (size_t)z * 1048576;
    const float* bias  = (z == 0) ? bias0 : (z == 1) ? bias1 : bias2;
    void* out          = (z == 0) ? out0 : (z == 1) ? out1 : out2;
    const float scale  = (multi && z == 0) ? 0.18033688f : 1.0f;  // 0.125*log2e
    const int mode     = multi ? ((z == 2) ? 2 : 1) : 0;

    // XCD-aware remap of (x,y) -> (m_tile, n_tile); bijective on 8x64 grid
    const int id  = blockIdx.x + 8 * blockIdx.y;   // linear%8 == x == XCD
    const int m0 = ((id & 7) * 8 + ((id >> 3) & 7)) * 128;
    const int n0 = (id >> 6) * 128;

    __shared__ __align__(16) uint16_t As[128 * 64];   // 16 KB
    __shared__ __align__(16) uint16_t Bs[128 * 64];   // 16 KB

    const int t    = threadIdx.x;
    const int w    = t >> 6;
    const int lane = t & 63;
    const int ln   = lane & 15;
    const int quad = lane >> 4;
    const int wr   = w >> 1;
    const int wc   = w & 1;

    f32x4 acc[4][4];
    const f32x4 z4 = {0.f, 0.f, 0.f, 0.f};
#pragma unroll
    for (int i = 0; i < 4; ++i)
#pragma unroll
        for (int j = 0; j < 4; ++j) acc[i][j] = z4;

    const char* Ag = (const char*)(A  + (size_t)m0 * E_);
    const char* Bg = (const char*)(Bw + (size_t)n0 * E_);
    const int rsub = lane >> 3;                         // 0..7
    const int colb = ((lane & 7) ^ rsub) * 16;          // swizzled source chunk

    for (int kk = 0; kk < E_; kk += 64) {
#pragma unroll
        for (int c = 0; c < 4; ++c) {
            glds16(Ag + (size_t)(c * 32 + w * 8 + rsub) * 2048 + kk * 2 + colb,
                   (char*)As + c * 4096 + w * 1024);
            glds16(Bg + (size_t)(c * 32 + w * 8 + rsub) * 2048 + kk * 2 + colb,
                   (char*)Bs + c * 4096 + w * 1024);
        }
        __syncthreads();

#pragma unroll
        for (int ks = 0; ks < 2; ++ks) {
            bf16x8 af[4], bf[4];
#pragma unroll
            for (int mt = 0; mt < 4; ++mt)
                af[mt] = *(const bf16x8*)&As[(wr * 64 + mt * 16 + ln) * 64 +
                                             (((ks * 4 + quad) ^ (ln & 7)) * 8)];
#pragma unroll
            for (int nt = 0; nt < 4; ++nt)
                bf[nt] = *(const bf16x8*)&Bs[(wc * 64 + nt * 16 + ln) * 64 +
                                             (((ks * 4 + quad) ^ (ln & 7)) * 8)];
#pragma unroll
            for (int mt = 0; mt < 4; ++mt)
#pragma unroll
                for (int nt = 0; nt < 4; ++nt)
                    acc[mt][nt] = __builtin_amdgcn_mfma_f32_16x16x32_bf16(
                        af[mt], bf[nt], acc[mt][nt], 0, 0, 0);
        }
        __syncthreads();
    }

    // epilogue; C/D layout: row = quad*4 + r, col = ln
#pragma unroll
    for (int mt = 0; mt < 4; ++mt) {
        const int rowb = m0 + wr * 64 + mt * 16 + quad * 4;
#pragma unroll
        for (int nt = 0; nt < 4; ++nt) {
            const int col = n0 + wc * 64 + nt * 16 + ln;
            const float bsum = bias[col];
            if (mode == 2) {
                int bb = rowb >> 11, s0 = rowb & 2047, hh = col >> 6, d = col & 63;
                float v0 = acc[mt][nt][0] + bsum, v1 = acc[mt][nt][1] + bsum;
                float v2 = acc[mt][nt][2] + bsum, v3 = acc[mt][nt][3] + bsum;
                uint2 o; o.x = pack2(v0, v1); o.y = pack2(v2, v3);
                *(uint2*)((uint16_t*)out + (((size_t)bb * H_ + hh) * DH_ + d) * S_ + s0) = o;
            } else {
#pragma unroll
                for (int r = 0; r < 4; ++r) {
                    float vv = (acc[mt][nt][r] + bsum) * scale;
                    int rr = rowb + r;
                    if (mode == 1) {
                        int bb = rr >> 11, s = rr & 2047, hh = col >> 6, d = col & 63;
                        ((uint16_t*)out)[(((size_t)bb * H_ + hh) * S_ + s) * DH_ + d] = f2bf(vv);
                    } else {
                        ((float*)out)[(size_t)rr * E_ + col] = vv;
                    }
                }
            }
        }
    }
}

// ---------------------------------------------------------------------------
// Kernel 3: flash attention, 256-row Q-blocks, m-split waves, DOUBLE-BUFFERED
// K/V LDS -> ONE barrier per tile with staging latency fully hidden.
//
// Block = 256 q-rows of one (b,h); wave w owns rows [w*64,+64).  Per tile:
// stage(it+1) into buf^1 (8 glds/wave), compute tile it from buf, then a
// single __syncthreads() (its compiler-emitted vmcnt drain lands ~1300cy
// after the glds issue -> free).  K: even/odd row interleave + XOR chunk
// swizzle; V^T: chunk^row swizzle.  Shared by all 4 waves (real reuse).
//
// P buffer is a 2-slot half-buffer (slot = mt&1, 16 rows each): per substrip
// we process mt-pairs {0,1} then {2,3} as {exp+pack -> PV}; slot reuse is
// safe because write(mt+2) follows read(mt) in program order (wave-private,
// same base pointer -> compiler orders via lgkmcnt).
//
// LDS: K 2x16K | V^T 2x16K | P 4x(32x36) u16 = 9216  -> 74752 B, 2 blk/CU.
// Registers ~120 (unchanged structure), launch_bounds(256,2): no spill.
// Grid 512 = 8 qt x 64 bh, XCD swizzle: 8 bh per XCD -> 4MB K/V = own L2.
// ---------------------------------------------------------------------------
__global__ __launch_bounds__(256, 2)
void attn_kernel(const uint16_t* __restrict__ qb, const uint16_t* __restrict__ kb,
                 const uint16_t* __restrict__ vtb, const uint32_t* __restrict__ mbits,
                 uint16_t* __restrict__ attn_out) {
    const int wg   = blockIdx.x;                // 0..511
    const int xcd  = wg & 7;
    const int rest = wg >> 3;                   // 0..63
    const int qt8  = rest & 7;                  // 256-row q block
    const int bh   = ((rest >> 3) << 3) | xcd;  // 0..63
    const int b    = bh >> 4, h = bh & 15;

    __shared__ __align__(16) char smem[74752];
    // K bufs: 0, 16384 | V^T bufs: 32768, 49152 | P: 65536 (9216 B)
    uint16_t* p_all = (uint16_t*)(smem + 65536);

    const int t    = threadIdx.x;
    const int w    = t >> 6;
    const int lane = t & 63;
    const int ln   = lane & 15;
    const int quad = lane >> 4;
    const int ln2  = ln << 1;

    const char* qg  = (const char*)(qb  + ((size_t)bh * S_ + qt8 * 256) * DH_);
    const char* kg  = (const char*)(kb  + (size_t)bh * S_ * DH_);
    const char* vtg = (const char*)(vtb + (size_t)bh * DH_ * S_);

    // ---- Q A-frags direct from global: wave's own 64 rows
    bf16x8 aq[4][2];
#pragma unroll
    for (int mt = 0; mt < 4; ++mt)
#pragma unroll
        for (int ks = 0; ks < 2; ++ks)
            aq[mt][ks] = *(const bf16x8*)(qg + (size_t)(w * 64 + mt * 16 + ln) * 128 +
                                          ks * 64 + quad * 16);

    f32x4 acc_o[4][4];
    const f32x4 z4 = {0.f, 0.f, 0.f, 0.f};
#pragma unroll
    for (int mt = 0; mt < 4; ++mt)
#pragma unroll
        for (int nt = 0; nt < 4; ++nt) acc_o[mt][nt] = z4;
    float lr[4][4];
#pragma unroll
    for (int mt = 0; mt < 4; ++mt)
#pragma unroll
        for (int r = 0; r < 4; ++r) lr[mt][r] = 0.f;

    uint16_t* pw = p_all + w * 1152;            // 2 slots x 16 rows x 36 u16
    // transposed mask base for this (b,qt8,wave,quad)
    const uint32_t* mw = mbits + (size_t)(b * 8 + qt8) * 16384 + w * 4096 + quad * 16;

    const int rsub = lane >> 3;                 // 0..7
    const int kcol = ((lane & 7) ^ rsub) * 16;  // swizzled source chunk (K)
    const int vrow = w * 16 + (lane >> 4);      // base d-row this lane stages (V)

    // ---- staging macro: tile -> buffer bufsel (8 glds/wave)
    auto stage = [&](int tile, int bufsel) {
        const char* kt = kg + (size_t)tile * 16384;
        char* kbase = smem + bufsel * 16384 + w * 4096;
#pragma unroll
        for (int c = 0; c < 4; ++c) {
            const int p    = c * 8 + rsub;                      // 0..31
            const int jrow = (p < 16) ? (2 * p) : (2 * p - 31); // even/odd perm
            glds16(kt + (size_t)(w * 32 + jrow) * 128 + kcol, kbase + c * 1024);
        }
        char* vbase = smem + 32768 + bufsel * 16384;
#pragma unroll
        for (int c = 0; c < 4; ++c) {
            int row = vrow + c * 4;
            int gch = (lane & 15) ^ (row & 15);
            glds16(vtg + (size_t)row * (S_ * 2) + tile * 256 + gch * 16,
                   vbase + (w * 16 + c * 4) * 256);
        }
    };

    stage(0, 0);
    __syncthreads();    // drain prologue staging

    for (int it = 0; it < 16; ++it) {
        const int cur = it & 1;
        if (it < 15) stage(it + 1, cur ^ 1);   // hidden under this tile's compute

        const uint16_t* k_lds  = (const uint16_t*)(smem + cur * 16384);
        const uint16_t* vt_lds = (const uint16_t*)(smem + 32768 + cur * 16384);

        // ---- 4 substrips of 32 j each
#pragma unroll
        for (int js = 0; js < 4; ++js) {
            // mask words: 4 x dwordx4 (r innermost), broadcast within quad
            uint4 mk4[4];
#pragma unroll
            for (int mt = 0; mt < 4; ++mt)
                mk4[mt] = *(const uint4*)(mw + js * 1024 + it * 64 + mt * 4);
            // V^T B-frags for this substrip
            bf16x8 bv[4];
#pragma unroll
            for (int nt = 0; nt < 4; ++nt)
                bv[nt] = *(const bf16x8*)&vt_lds[(nt * 16 + ln) * 128 +
                                                 (((js * 4 + quad) ^ ln) * 8)];

            // scores: 64 q-rows x 32 j, 16 MFMAs
            f32x4 sc[4][2];
#pragma unroll
            for (int mt = 0; mt < 4; ++mt) { sc[mt][0] = z4; sc[mt][1] = z4; }
#pragma unroll
            for (int ks = 0; ks < 2; ++ks) {
                bf16x8 bk0 = *(const bf16x8*)&k_lds[(js * 32 + ln) * 64 +
                                                    (((ks * 4 + quad) ^ (ln & 7)) * 8)];
                bf16x8 bk1 = *(const bf16x8*)&k_lds[(js * 32 + 16 + ln) * 64 +
                                                    (((ks * 4 + quad) ^ (ln & 7)) * 8)];
#pragma unroll
                for (int mt = 0; mt < 4; ++mt) {
                    sc[mt][0] = __builtin_amdgcn_mfma_f32_16x16x32_bf16(aq[mt][ks], bk0, sc[mt][0], 0, 0, 0);
                    sc[mt][1] = __builtin_amdgcn_mfma_f32_16x16x32_bf16(aq[mt][ks], bk1, sc[mt][1], 0, 0, 0);
                }
            }

            // ---- two mt-pair phases: {exp+pack slot mh} then {PV slot mh}
#pragma unroll
            for (int hf = 0; hf < 2; ++hf) {
#pragma unroll
                for (int mh = 0; mh < 2; ++mh) {
                    const int mt = hf * 2 + mh;
                    const uint32_t* mkp = (const uint32_t*)&mk4[mt];
#pragma unroll
                    for (int r = 0; r < 4; ++r) {
                        uint32_t sh = mkp[r] >> ln2;
                        float e0 = (sh & 1u) ? 0.f : exp2_fast(sc[mt][0][r]);
                        float e1 = (sh & 2u) ? 0.f : exp2_fast(sc[mt][1][r]);
                        lr[mt][r] += e0 + e1;
                        *(uint32_t*)&pw[(mh * 16 + quad * 4 + r) * 36 + ln2] = cvt_pk_bf16(e0, e1);
                    }
                }
                // PV: O[q][d] += P[q][j] * V^T[d][j], 8 MFMAs per phase
#pragma unroll
                for (int mh = 0; mh < 2; ++mh) {
                    const int mt = hf * 2 + mh;
                    bf16x4 lo = *(const bf16x4*)&pw[(mh * 16 + ln) * 36 + quad * 8];
                    bf16x4 hi = *(const bf16x4*)&pw[(mh * 16 + ln) * 36 + quad * 8 + 4];
                    bf16x8 ap = __builtin_shufflevector(lo, hi, 0, 1, 2, 3, 4, 5, 6, 7);
#pragma unroll
                    for (int nt = 0; nt < 4; ++nt)
                        acc_o[mt][nt] = __builtin_amdgcn_mfma_f32_16x16x32_bf16(ap, bv[nt], acc_o[mt][nt], 0, 0, 0);
                }
            }
        }
        __syncthreads();   // single barrier: joins waves + drains next-tile glds
    }

    // ---- reduce l within wave (sum over ln bits -> full 2048-col row sum)
    float invl[4][4];
#pragma unroll
    for (int mt = 0; mt < 4; ++mt)
#pragma unroll
        for (int r = 0; r < 4; ++r) {
            float v = lr[mt][r];
            v += __shfl_xor(v, 1);
            v += __shfl_xor(v, 2);
            v += __shfl_xor(v, 4);
            v += __shfl_xor(v, 8);
            invl[mt][r] = 1.0f / v;
        }

    // ---- direct store (wave owns its rows; no cross-wave reduction)
    const size_t orow0 = (size_t)b * S_ + qt8 * 256 + w * 64;
#pragma unroll
    for (int mt = 0; mt < 4; ++mt)
#pragma unroll
        for (int r = 0; r < 4; ++r) {
            const size_t row = orow0 + mt * 16 + quad * 4 + r;
#pragma unroll
            for (int nt = 0; nt < 4; ++nt)
                attn_out[row * E_ + h * 64 + nt * 16 + ln] =
                    f2bf(acc_o[mt][nt][r] * invl[mt][r]);
        }
}

// ---------------------------------------------------------------------------
// Launcher.  Workspace layout (MB):
//   [0,8)    Wq,Wk,Wv,Wo bf16
//   [8,24)   query bf16    [24,40) key bf16    [40,56) value bf16
//   [56,72)  q proj bf16 [B,H,S,Dh] (scaled log2e/8)
//   [72,88)  k proj bf16 [B,H,S,Dh]
//   [88,104) v proj bf16 [B,H,Dh,S] (transposed)
//   [104,120) attn out bf16 [B*S, E]
//   [120,122) mask bitmask (transposed layout, 2 MB)
// ---------------------------------------------------------------------------
extern "C" void kernel_launch(void* const* d_in, const int* in_sizes, int n_in,
                              void* d_out, int out_size, void* d_ws, size_t ws_size,
                              hipStream_t stream) {
    const float* query = (const float*)d_in[0];
    const float* key_  = (const float*)d_in[1];
    const float* value = (const float*)d_in[2];
    const int*   mask  = (const int*)d_in[3];
    const float* Wq = (const float*)d_in[4];
    const float* bq = (const float*)d_in[5];
    const float* Wk = (const float*)d_in[6];
    const float* bk = (const float*)d_in[7];
    const float* Wv = (const float*)d_in[8];
    const float* bv = (const float*)d_in[9];
    const float* Wo = (const float*)d_in[10];
    const float* bo = (const float*)d_in[11];

    char* ws = (char*)d_ws;
    uint16_t* wbf   = (uint16_t*)ws;
    uint16_t* qa    = (uint16_t*)(ws + (8u   << 20));
    uint16_t* ka    = (uint16_t*)(ws + (24u  << 20));
    uint16_t* va    = (uint16_t*)(ws + (40u  << 20));
    uint16_t* qproj = (uint16_t*)(ws + (56u  << 20));
    uint16_t* kproj = (uint16_t*)(ws + (72u  << 20));
    uint16_t* vtp   = (uint16_t*)(ws + (88u  << 20));
    uint16_t* atto  = (uint16_t*)(ws + (104u << 20));
    uint32_t* mbits = (uint32_t*)(ws + (120u << 20));

    prep_kernel<<<14336, 256, 0, stream>>>(query, key_, value, Wq, Wk, Wv, Wo,
                                           wbf, qa, ka, va);
    mask_bits_kernel<<<65536, 256, 0, stream>>>(mask, mbits);

    // q/k/v projections in one launch (z selects input/weight/output)
    gemm_bt_kernel<<<dim3(E_ / 128, M_ / 128, 3), 256, 0, stream>>>(
        qa, ka, va, wbf, bq, bk, bv, qproj, kproj, vtp, 1);

    attn_kernel<<<dim3(512), 256, 0, stream>>>(
        qproj, kproj, vtp, mbits, atto);

    // final projection: A=atto, W=Wo (4th weight), fp32 out
    gemm_bt_kernel<<<dim3(E_ / 128, M_ / 128, 1), 256, 0, stream>>>(
        atto, atto, atto, wbf + 3145728, bo, bo, bo, d_out, d_out, d_out, 0);
}